// Round 3
// baseline (1015.295 us; speedup 1.0000x reference)
//
#include <hip/hip_runtime.h>

#define THREADS 256
#define NF 14      // input features
#define DIMOUT 16  // output dim
#define NPB 32     // nodes per bucket
#define BPT 4      // buckets per thread in bucket-scan (covers NB <= 4096)

// ---- detect whether edge_index buffer is int64 (odd int32 words all zero) ----
__global__ void k_detect(const int* __restrict__ e32, int* __restrict__ flag) {
    int is64 = 1;
    for (int i = 1; i < 64; i += 2) {
        if (e32[i] != 0) { is64 = 0; break; }
    }
    *flag = is64;
}

// ---- node in-degree (real edges; self-loop accounted as +1 in dinv) ----
__global__ void k_count(const void* __restrict__ edges, const int* __restrict__ flag,
                        int* __restrict__ counts, int E) {
    const bool is64 = (*flag != 0);
    const long long* e64 = (const long long*)edges;
    const int* e32 = (const int*)edges;
    int stride = gridDim.x * blockDim.x;
    for (int i = blockIdx.x * blockDim.x + threadIdx.x; i < E; i += stride) {
        int dst = is64 ? (int)e64[(size_t)E + i] : e32[(size_t)E + i];
        atomicAdd(&counts[dst], 1);
    }
}

// ---- single-block scan over bucket sums -> bucket entry bases ----
__global__ __launch_bounds__(1024) void k_bscan(const int* __restrict__ counts,
                                                int* __restrict__ bbase, int N, int E) {
    const int NB = (N + NPB - 1) / NPB;
    int t = threadIdx.x;
    int bs[BPT];
    int s = 0;
#pragma unroll
    for (int k = 0; k < BPT; ++k) {
        int b = t * BPT + k;
        int c = 0;
        if (b < NB) {
            int n0 = b * NPB, n1 = min(N, n0 + NPB);
            for (int n = n0; n < n1; ++n) c += counts[n];
        }
        bs[k] = c;
        s += c;
    }
    __shared__ int sm[1024];
    sm[t] = s;
    __syncthreads();
    for (int d = 1; d < 1024; d <<= 1) {
        int v = (t >= d) ? sm[t - d] : 0;
        __syncthreads();
        sm[t] += v;
        __syncthreads();
    }
    int run = (t > 0) ? sm[t - 1] : 0;
#pragma unroll
    for (int k = 0; k < BPT; ++k) {
        int b = t * BPT + k;
        if (b < NB) {
            bbase[b] = run;
            run += bs[k];
        }
    }
    if (t == 0) bbase[NB] = E;
}

// ---- bin edges into buckets: packed entry = (dst_local << 17) | src ----
__global__ void k_binA(const void* __restrict__ edges, const int* __restrict__ flag,
                       const int* __restrict__ bbase, int* __restrict__ cur,
                       unsigned int* __restrict__ pairs, int E) {
    const bool is64 = (*flag != 0);
    const long long* e64 = (const long long*)edges;
    const int* e32 = (const int*)edges;
    int stride = gridDim.x * blockDim.x;
    for (int i = blockIdx.x * blockDim.x + threadIdx.x; i < E; i += stride) {
        int src, dst;
        if (is64) {
            src = (int)e64[i];
            dst = (int)e64[(size_t)E + i];
        } else {
            src = e32[i];
            dst = e32[(size_t)E + i];
        }
        int b = dst / NPB;
        int pos = bbase[b] + atomicAdd(&cur[b], 1);
        pairs[pos] = (unsigned int)src | ((unsigned int)(dst & (NPB - 1)) << 17);
    }
}

// ---- dinv + pad x rows to 16 floats ----
__global__ void k_prep(const float* __restrict__ x, const int* __restrict__ counts,
                       float* __restrict__ dinv, float* __restrict__ x_pad, int N) {
    int i = blockIdx.x * 256 + threadIdx.x;
    if (i >= N * 16) return;
    int n = i >> 4, f = i & 15;
    if (f == 0) dinv[n] = rsqrtf((float)(counts[n] + 1));
    x_pad[i] = (f < NF) ? x[(size_t)n * NF + f] : 0.f;
}

// ---- one hop: one block per 32-node bucket, edge-parallel, LDS accumulate ----
// FINAL=1 fuses out = x2 @ W^T + b into the writeout.
template <int FINAL>
__global__ __launch_bounds__(256) void k_hop(const unsigned int* __restrict__ pairs,
                                             const int* __restrict__ bbase,
                                             const float* __restrict__ dinv,
                                             const float* __restrict__ xin_pad,
                                             const float* __restrict__ W,
                                             const float* __restrict__ bias,
                                             float* __restrict__ out, int N) {
    const int b = blockIdx.x;
    const int node0 = b * NPB;
    const int nloc = min(NPB, N - node0);
    const int e0 = bbase[b];
    const int e1 = bbase[b + 1];
    __shared__ float acc[NPB][17];
    __shared__ float Wl[DIMOUT][NF];
    __shared__ float bl[DIMOUT];
    const int tid = threadIdx.x;
    for (int i = tid; i < NPB * 17; i += 256) ((float*)acc)[i] = 0.f;
    if (FINAL) {
        if (tid < DIMOUT * NF) ((float*)Wl)[tid] = W[tid];
        if (tid < DIMOUT) bl[tid] = bias[tid];
    }
    __syncthreads();
    const int f = tid & 15;   // feature lane
    const int es = tid >> 4;  // edge sub-index (0..15)
    for (int e = e0 + es; e < e1; e += 16) {
        unsigned int p = pairs[e];           // broadcast across 16 lanes
        int src = (int)(p & 0x1FFFFu);
        int d = (int)(p >> 17);
        float v = dinv[src] * xin_pad[(size_t)src * 16 + f];  // 64B coalesced
        atomicAdd(&acc[d][f], v);
    }
    __syncthreads();
    // finalize: x2[n][f] = dn * (acc + dn * x_self)
    for (int i = tid; i < nloc * 16; i += 256) {
        int d = i >> 4, ff = i & 15;
        int n = node0 + d;
        float dn = dinv[n];
        acc[d][ff] = dn * (acc[d][ff] + dn * xin_pad[(size_t)n * 16 + ff]);
    }
    __syncthreads();
    if (!FINAL) {
        for (int i = tid; i < nloc * 16; i += 256) {
            int d = i >> 4, ff = i & 15;
            out[(size_t)(node0 + d) * 16 + ff] = acc[d][ff];
        }
    } else {
        for (int i = tid; i < nloc * 16; i += 256) {
            int d = i >> 4, j = i & 15;
            float r = bl[j];
#pragma unroll
            for (int ff = 0; ff < NF; ++ff) r += acc[d][ff] * Wl[j][ff];
            out[(size_t)(node0 + d) * DIMOUT + j] = r;
        }
    }
}

extern "C" void kernel_launch(void* const* d_in, const int* in_sizes, int n_in,
                              void* d_out, int out_size, void* d_ws, size_t ws_size,
                              hipStream_t stream) {
    const float* x = (const float*)d_in[0];
    const void* edges = d_in[1];
    const float* W = (const float*)d_in[2];
    const float* b = (const float*)d_in[3];
    float* out = (float*)d_out;

    const int N = in_sizes[0] / NF;  // 100000
    const int E = in_sizes[1] / 2;   // 3200000
    const int NB = (N + NPB - 1) / NPB;

    char* ws = (char*)d_ws;
    size_t o = 0;
    auto alloc = [&](size_t bytes) -> void* {
        o = (o + 255) & ~(size_t)255;
        void* p = ws + o;
        o += bytes;
        return p;
    };
    int* flag = (int*)alloc(16);
    int* cz = (int*)alloc(((size_t)N + NB) * sizeof(int));  // counts | cur (zeroed)
    int* counts = cz;
    int* cur = cz + N;
    int* bbase = (int*)alloc(((size_t)NB + 1) * sizeof(int));
    float* dinv = (float*)alloc((size_t)N * sizeof(float));
    unsigned int* pairs = (unsigned int*)alloc((size_t)E * sizeof(unsigned int));
    float* x_pad = (float*)alloc((size_t)N * 16 * sizeof(float));
    float* x1 = (float*)alloc((size_t)N * 16 * sizeof(float));
    (void)ws_size;
    (void)n_in;
    (void)out_size;

    hipMemsetAsync(cz, 0, ((size_t)N + NB) * sizeof(int), stream);
    k_detect<<<1, 1, 0, stream>>>((const int*)edges, flag);
    k_count<<<2048, THREADS, 0, stream>>>(edges, flag, counts, E);
    k_bscan<<<1, 1024, 0, stream>>>(counts, bbase, N, E);
    k_binA<<<2048, THREADS, 0, stream>>>(edges, flag, bbase, cur, pairs, E);
    k_prep<<<(N * 16 + 255) / 256, 256, 0, stream>>>(x, counts, dinv, x_pad, N);

    k_hop<0><<<NB, 256, 0, stream>>>(pairs, bbase, dinv, x_pad, nullptr, nullptr, x1, N);
    k_hop<1><<<NB, 256, 0, stream>>>(pairs, bbase, dinv, x1, W, b, out, N);
}

// Round 4
// 228.062 us; speedup vs baseline: 4.4518x; 4.4518x over previous
//
#include <hip/hip_runtime.h>

#define NF 14
#define DIMOUT 16
#define BSH 9         // 512 nodes per bucket
#define NPBKT 512     // nodes per bucket
#define NBKT 256      // allocated buckets (used: ceil(N/512) = 196)
#define C1 4096       // edges per scatter1 block

// ---- detect whether edge_index buffer is int64 (odd int32 words all zero) ----
__global__ void k_detect(const int* __restrict__ e32, int* __restrict__ flag) {
    int is64 = 1;
    for (int i = 1; i < 64; i += 2) {
        if (e32[i] != 0) { is64 = 0; break; }
    }
    *flag = is64;
}

// ---- bucket-level histogram of dst ----
__global__ __launch_bounds__(256) void k_bhist(const void* __restrict__ edges,
                                               const int* __restrict__ flag,
                                               int* __restrict__ bhist, int E) {
    __shared__ int h[NBKT];
    int t = threadIdx.x;
    h[t] = 0;
    __syncthreads();
    const bool is64 = (*flag != 0);
    const long long* e64 = (const long long*)edges;
    const int* e32 = (const int*)edges;
    int stride = gridDim.x * blockDim.x;
    for (int i = blockIdx.x * blockDim.x + t; i < E; i += stride) {
        int dst = is64 ? (int)e64[(size_t)E + i] : e32[(size_t)E + i];
        atomicAdd(&h[dst >> BSH], 1);
    }
    __syncthreads();
    if (h[t]) atomicAdd(&bhist[t], h[t]);
}

// ---- scan bucket histogram -> region bases + live cursors ----
__global__ __launch_bounds__(NBKT) void k_bscan(const int* __restrict__ bhist,
                                                int* __restrict__ gregion,
                                                int* __restrict__ gcur, int E) {
    __shared__ int sm[NBKT];
    int t = threadIdx.x;
    int v = bhist[t];
    sm[t] = v;
    __syncthreads();
    for (int d = 1; d < NBKT; d <<= 1) {
        int u = (t >= d) ? sm[t - d] : 0;
        __syncthreads();
        sm[t] += u;
        __syncthreads();
    }
    int ex = sm[t] - v;
    gregion[t] = ex;
    gcur[t] = ex;
    if (t == NBKT - 1) gregion[NBKT] = sm[t];  // == E
}

// ---- pass 1: block-local LDS counting sort by bucket, burst-copy out ----
// packed entry: (dst & 511) << 17 | src   (src < 131072)
__global__ __launch_bounds__(256) void k_scatter1(const void* __restrict__ edges,
                                                  const int* __restrict__ flag,
                                                  int* __restrict__ gcur,
                                                  unsigned int* __restrict__ pairs, int E) {
    __shared__ unsigned int raw[C1];
    __shared__ unsigned int srt[C1];
    __shared__ unsigned short bkt[C1];
    __shared__ unsigned short sbk[C1];
    __shared__ int hist[NBKT], scn[NBKT], gb[NBKT], cur[NBKT];
    const bool is64 = (*flag != 0);
    const long long* e64 = (const long long*)edges;
    const int* e32 = (const int*)edges;
    const int t = threadIdx.x;
    const int base = blockIdx.x * C1;
    const int cnt = min(C1, E - base);
    hist[t] = 0;
    cur[t] = 0;
    __syncthreads();
    for (int j = t; j < cnt; j += 256) {
        int i = base + j;
        int src, dst;
        if (is64) {
            src = (int)e64[i];
            dst = (int)e64[(size_t)E + i];
        } else {
            src = e32[i];
            dst = e32[(size_t)E + i];
        }
        int b = dst >> BSH;
        raw[j] = (unsigned int)src | ((unsigned int)(dst & (NPBKT - 1)) << 17);
        bkt[j] = (unsigned short)b;
        atomicAdd(&hist[b], 1);
    }
    __syncthreads();
    int v = hist[t];
    scn[t] = v;
    __syncthreads();
    for (int d = 1; d < NBKT; d <<= 1) {
        int u = (t >= d) ? scn[t - d] : 0;
        __syncthreads();
        scn[t] += u;
        __syncthreads();
    }
    int ex = scn[t] - v;
    gb[t] = v ? atomicAdd(&gcur[t], v) : 0;  // reserve run in bucket t's region
    __syncthreads();
    scn[t] = ex;
    __syncthreads();
    for (int j = t; j < cnt; j += 256) {
        int b = bkt[j];
        int r = atomicAdd(&cur[b], 1);
        int pos = scn[b] + r;
        srt[pos] = raw[j];
        sbk[pos] = (unsigned short)b;
    }
    __syncthreads();
    for (int j = t; j < cnt; j += 256) {
        int b = sbk[j];
        pairs[gb[b] + (j - scn[b])] = srt[j];  // sequential within runs
    }
}

// ---- pass 2: per-bucket LDS counting sort -> node CSR + offsets + dinv ----
__global__ __launch_bounds__(256) void k_sort2(const unsigned int* __restrict__ pairs,
                                               const int* __restrict__ gregion,
                                               int* __restrict__ srcs,
                                               int* __restrict__ offsets,
                                               float* __restrict__ dinv, int N, int E) {
    __shared__ int cnt[NPBKT], off[NPBKT], cur[NPBKT];
    __shared__ int sm[256];
    const int b = blockIdx.x, t = threadIdx.x;
    const int e0 = gregion[b], e1 = gregion[b + 1];
    cnt[2 * t] = 0;
    cnt[2 * t + 1] = 0;
    cur[2 * t] = 0;
    cur[2 * t + 1] = 0;
    __syncthreads();
    for (int e = e0 + t; e < e1; e += 256) atomicAdd(&cnt[pairs[e] >> 17], 1);
    __syncthreads();
    int h0 = cnt[2 * t], h1 = cnt[2 * t + 1];
    int s = h0 + h1;
    sm[t] = s;
    __syncthreads();
    for (int d = 1; d < 256; d <<= 1) {
        int u = (t >= d) ? sm[t - d] : 0;
        __syncthreads();
        sm[t] += u;
        __syncthreads();
    }
    int ex = sm[t] - s;
    off[2 * t] = ex;
    off[2 * t + 1] = ex + h0;
    __syncthreads();
    for (int l = t; l < NPBKT; l += 256) {
        int n = (b << BSH) + l;
        if (n < N) {
            offsets[n] = e0 + off[l];
            dinv[n] = rsqrtf((float)(cnt[l] + 1));
        }
    }
    if (b == 0 && t == 0) offsets[N] = E;
    for (int e = e0 + t; e < e1; e += 256) {
        unsigned int p = pairs[e];
        int l = p >> 17;
        int r = atomicAdd(&cur[l], 1);
        srcs[e0 + off[l] + r] = (int)(p & 0x1FFFFu);  // L2-local scatter (64KB window)
    }
}

// ---- u0 = dinv * x, padded to 16 floats/row ----
__global__ void k_prep(const float* __restrict__ x, const float* __restrict__ dinv,
                       float* __restrict__ u0, int N) {
    int i = blockIdx.x * 256 + threadIdx.x;
    if (i >= N * 16) return;
    int n = i >> 4, f = i & 15;
    u0[i] = (f < NF) ? dinv[n] * x[(size_t)n * NF + f] : 0.f;
}

// ---- hop: wave per node, 4-way edge-parallel, pre-scaled rows ----
// HOP1: out = dinv^2 * (W . acc)   (u1, pre-scaled for next hop)
// HOP2: out = dinv * acc + bias
template <int HOP1>
__global__ __launch_bounds__(256) void k_hop(const float* __restrict__ u,
                                             const int* __restrict__ srcs,
                                             const int* __restrict__ offsets,
                                             const float* __restrict__ dinv,
                                             const float* __restrict__ Wg,
                                             const float* __restrict__ bias,
                                             float* __restrict__ out, int N) {
    const int lane = threadIdx.x & 63;
    const int f = lane & 15;  // feature lane (also output dim j in epilogue)
    const int ep = lane >> 4; // 0..3 edge-parallel subgroup
    const int wid = threadIdx.x >> 6;
    int n = blockIdx.x * 4 + wid;

    float Wreg[NF];
    float breg = 0.f;
    if (HOP1) {
#pragma unroll
        for (int ff = 0; ff < NF; ++ff) Wreg[ff] = Wg[f * NF + ff];
    } else {
        breg = bias[f];
    }

    float acc = 0.f;
    int beg = 0, end = 0;
    if (n < N) {
        beg = offsets[n];
        end = offsets[n + 1];
    }
    int e = beg + ep;
    for (; e + 12 < end; e += 16) {
        int s0 = srcs[e];
        int s1 = srcs[e + 4];
        int s2 = srcs[e + 8];
        int s3 = srcs[e + 12];
        float a0 = u[(size_t)s0 * 16 + f];
        float a1 = u[(size_t)s1 * 16 + f];
        float a2 = u[(size_t)s2 * 16 + f];
        float a3 = u[(size_t)s3 * 16 + f];
        acc += a0 + a1 + a2 + a3;
    }
    for (; e < end; e += 4) acc += u[(size_t)srcs[e] * 16 + f];
    acc += __shfl_xor(acc, 16);
    acc += __shfl_xor(acc, 32);
    if (n >= N) return;
    acc += u[(size_t)n * 16 + f];  // self loop
    float dn = dinv[n];
    if (HOP1) {
        float r = 0.f;
#pragma unroll
        for (int ff = 0; ff < NF; ++ff) {
            float af = __shfl(acc, ff);  // acc for feature ff lives in lane ff
            r += Wreg[ff] * af;
        }
        if (lane < 16) out[(size_t)n * 16 + lane] = dn * dn * r;
    } else {
        if (lane < 16) out[(size_t)n * 16 + lane] = dn * acc + breg;
    }
}

extern "C" void kernel_launch(void* const* d_in, const int* in_sizes, int n_in,
                              void* d_out, int out_size, void* d_ws, size_t ws_size,
                              hipStream_t stream) {
    const float* x = (const float*)d_in[0];
    const void* edges = d_in[1];
    const float* W = (const float*)d_in[2];
    const float* b = (const float*)d_in[3];
    float* out = (float*)d_out;

    const int N = in_sizes[0] / NF;  // 100000
    const int E = in_sizes[1] / 2;   // 3200000

    char* ws = (char*)d_ws;
    size_t o = 0;
    auto alloc = [&](size_t bytes) -> void* {
        o = (o + 255) & ~(size_t)255;
        void* p = ws + o;
        o += bytes;
        return p;
    };
    int* flag = (int*)alloc(16);
    int* bhist = (int*)alloc((size_t)NBKT * sizeof(int));
    int* gregion = (int*)alloc(((size_t)NBKT + 1) * sizeof(int));
    int* gcur = (int*)alloc((size_t)NBKT * sizeof(int));
    unsigned int* pairs = (unsigned int*)alloc((size_t)E * sizeof(unsigned int));
    int* srcs = (int*)alloc((size_t)E * sizeof(int));
    int* offsets = (int*)alloc(((size_t)N + 1) * sizeof(int));
    float* dinv = (float*)alloc((size_t)N * sizeof(float));
    float* u0 = (float*)alloc((size_t)N * 16 * sizeof(float));
    float* u1 = (float*)alloc((size_t)N * 16 * sizeof(float));
    (void)ws_size;
    (void)n_in;
    (void)out_size;

    hipMemsetAsync(bhist, 0, (size_t)NBKT * sizeof(int), stream);
    k_detect<<<1, 1, 0, stream>>>((const int*)edges, flag);
    k_bhist<<<512, 256, 0, stream>>>(edges, flag, bhist, E);
    k_bscan<<<1, NBKT, 0, stream>>>(bhist, gregion, gcur, E);
    k_scatter1<<<(E + C1 - 1) / C1, 256, 0, stream>>>(edges, flag, gcur, pairs, E);
    k_sort2<<<(N + NPBKT - 1) >> BSH, 256, 0, stream>>>(pairs, gregion, srcs, offsets, dinv, N, E);
    k_prep<<<(N * 16 + 255) / 256, 256, 0, stream>>>(x, dinv, u0, N);

    int hopgrid = (N + 3) / 4;
    k_hop<1><<<hopgrid, 256, 0, stream>>>(u0, srcs, offsets, dinv, W, nullptr, u1, N);
    k_hop<0><<<hopgrid, 256, 0, stream>>>(u1, srcs, offsets, dinv, nullptr, b, out, N);
}

// Round 5
// 207.813 us; speedup vs baseline: 4.8856x; 1.0974x over previous
//
#include <hip/hip_runtime.h>
#include <hip/hip_fp16.h>

#define NF 14
#define DIMOUT 16
#define BSH 9         // 512 nodes per bucket
#define NPBKT 512     // nodes per bucket
#define NBKT 256      // allocated buckets (used: ceil(N/512) = 196)
#define C1 4096       // edges per scatter1 block

// ---- detect whether edge_index buffer is int64 (odd int32 words all zero) ----
__global__ void k_detect(const int* __restrict__ e32, int* __restrict__ flag) {
    int is64 = 1;
    for (int i = 1; i < 64; i += 2) {
        if (e32[i] != 0) { is64 = 0; break; }
    }
    *flag = is64;
}

// ---- bucket-level histogram of dst ----
__global__ __launch_bounds__(256) void k_bhist(const void* __restrict__ edges,
                                               const int* __restrict__ flag,
                                               int* __restrict__ bhist, int E) {
    __shared__ int h[NBKT];
    int t = threadIdx.x;
    h[t] = 0;
    __syncthreads();
    const bool is64 = (*flag != 0);
    const long long* e64 = (const long long*)edges;
    const int* e32 = (const int*)edges;
    int stride = gridDim.x * blockDim.x;
    for (int i = blockIdx.x * blockDim.x + t; i < E; i += stride) {
        int dst = is64 ? (int)e64[(size_t)E + i] : e32[(size_t)E + i];
        atomicAdd(&h[dst >> BSH], 1);
    }
    __syncthreads();
    if (h[t]) atomicAdd(&bhist[t], h[t]);
}

// ---- scan bucket histogram -> region bases + live cursors ----
__global__ __launch_bounds__(NBKT) void k_bscan(const int* __restrict__ bhist,
                                                int* __restrict__ gregion,
                                                int* __restrict__ gcur, int E) {
    __shared__ int sm[NBKT];
    int t = threadIdx.x;
    int v = bhist[t];
    sm[t] = v;
    __syncthreads();
    for (int d = 1; d < NBKT; d <<= 1) {
        int u = (t >= d) ? sm[t - d] : 0;
        __syncthreads();
        sm[t] += u;
        __syncthreads();
    }
    int ex = sm[t] - v;
    gregion[t] = ex;
    gcur[t] = ex;
    if (t == NBKT - 1) gregion[NBKT] = sm[t];  // == E
}

// ---- pass 1: block-local LDS counting sort by bucket, burst-copy out ----
// packed entry: (dst & 511) << 17 | src   (src < 131072)
__global__ __launch_bounds__(256) void k_scatter1(const void* __restrict__ edges,
                                                  const int* __restrict__ flag,
                                                  int* __restrict__ gcur,
                                                  unsigned int* __restrict__ pairs, int E) {
    __shared__ unsigned int raw[C1];
    __shared__ unsigned int srt[C1];
    __shared__ unsigned short bkt[C1];
    __shared__ unsigned short sbk[C1];
    __shared__ int hist[NBKT], scn[NBKT], gb[NBKT], cur[NBKT];
    const bool is64 = (*flag != 0);
    const long long* e64 = (const long long*)edges;
    const int* e32 = (const int*)edges;
    const int t = threadIdx.x;
    const int base = blockIdx.x * C1;
    const int cnt = min(C1, E - base);
    hist[t] = 0;
    cur[t] = 0;
    __syncthreads();
    for (int j = t; j < cnt; j += 256) {
        int i = base + j;
        int src, dst;
        if (is64) {
            src = (int)e64[i];
            dst = (int)e64[(size_t)E + i];
        } else {
            src = e32[i];
            dst = e32[(size_t)E + i];
        }
        int b = dst >> BSH;
        raw[j] = (unsigned int)src | ((unsigned int)(dst & (NPBKT - 1)) << 17);
        bkt[j] = (unsigned short)b;
        atomicAdd(&hist[b], 1);
    }
    __syncthreads();
    int v = hist[t];
    scn[t] = v;
    __syncthreads();
    for (int d = 1; d < NBKT; d <<= 1) {
        int u = (t >= d) ? scn[t - d] : 0;
        __syncthreads();
        scn[t] += u;
        __syncthreads();
    }
    int ex = scn[t] - v;
    gb[t] = v ? atomicAdd(&gcur[t], v) : 0;  // reserve run in bucket t's region
    __syncthreads();
    scn[t] = ex;
    __syncthreads();
    for (int j = t; j < cnt; j += 256) {
        int b = bkt[j];
        int r = atomicAdd(&cur[b], 1);
        int pos = scn[b] + r;
        srt[pos] = raw[j];
        sbk[pos] = (unsigned short)b;
    }
    __syncthreads();
    for (int j = t; j < cnt; j += 256) {
        int b = sbk[j];
        pairs[gb[b] + (j - scn[b])] = srt[j];  // sequential within runs
    }
}

// ---- pass 2: per-bucket LDS counting sort -> node CSR + offsets + dinv ----
__global__ __launch_bounds__(256) void k_sort2(const unsigned int* __restrict__ pairs,
                                               const int* __restrict__ gregion,
                                               int* __restrict__ srcs,
                                               int* __restrict__ offsets,
                                               float* __restrict__ dinv, int N, int E) {
    __shared__ int cnt[NPBKT], off[NPBKT], cur[NPBKT];
    __shared__ int sm[256];
    const int b = blockIdx.x, t = threadIdx.x;
    const int e0 = gregion[b], e1 = gregion[b + 1];
    cnt[2 * t] = 0;
    cnt[2 * t + 1] = 0;
    cur[2 * t] = 0;
    cur[2 * t + 1] = 0;
    __syncthreads();
    for (int e = e0 + t; e < e1; e += 256) atomicAdd(&cnt[pairs[e] >> 17], 1);
    __syncthreads();
    int h0 = cnt[2 * t], h1 = cnt[2 * t + 1];
    int s = h0 + h1;
    sm[t] = s;
    __syncthreads();
    for (int d = 1; d < 256; d <<= 1) {
        int u = (t >= d) ? sm[t - d] : 0;
        __syncthreads();
        sm[t] += u;
        __syncthreads();
    }
    int ex = sm[t] - s;
    off[2 * t] = ex;
    off[2 * t + 1] = ex + h0;
    __syncthreads();
    for (int l = t; l < NPBKT; l += 256) {
        int n = (b << BSH) + l;
        if (n < N) {
            offsets[n] = e0 + off[l];
            dinv[n] = rsqrtf((float)(cnt[l] + 1));
        }
    }
    if (b == 0 && t == 0) offsets[N] = E;
    for (int e = e0 + t; e < e1; e += 256) {
        unsigned int p = pairs[e];
        int l = p >> 17;
        int r = atomicAdd(&cur[l], 1);
        srcs[e0 + off[l] + r] = (int)(p & 0x1FFFFu);  // L2-local scatter (64KB window)
    }
}

// ---- u0 = fp16(dinv * x), padded to 16 halves/row ----
__global__ void k_prep(const float* __restrict__ x, const float* __restrict__ dinv,
                       __half* __restrict__ u0, int N) {
    int i = blockIdx.x * 256 + threadIdx.x;  // feature-pair index
    if (i >= N * 8) return;
    int n = i >> 3, f2 = i & 7;
    float d = dinv[n];
    int f0 = 2 * f2, f1 = 2 * f2 + 1;
    float a = (f0 < NF) ? d * x[(size_t)n * NF + f0] : 0.f;
    float b = (f1 < NF) ? d * x[(size_t)n * NF + f1] : 0.f;
    *(__half2*)(u0 + (size_t)i * 2) = __halves2half2(__float2half(a), __float2half(b));
}

// ---- hop: wave per node, 8-way edge-parallel, fp16 rows, half2 lanes ----
// lane = ep*8 + fp;  fp = feature pair (0..7), ep = edge subgroup (0..7)
// HOP1: u1 = fp16( dinv^2 * (W . acc) )    HOP2: out = dinv * acc + bias  (fp32)
template <int HOP1>
__global__ __launch_bounds__(256) void k_hop(const __half* __restrict__ u,
                                             const int* __restrict__ srcs,
                                             const int* __restrict__ offsets,
                                             const float* __restrict__ dinv,
                                             const float* __restrict__ Wg,
                                             const float* __restrict__ bias,
                                             __half* __restrict__ outh,
                                             float* __restrict__ outf, int N) {
    const int lane = threadIdx.x & 63;
    const int fp = lane & 7;   // feature-pair lane
    const int ep = lane >> 3;  // 0..7 edge-parallel subgroup
    const int wid = threadIdx.x >> 6;
    const int n = blockIdx.x * 4 + wid;

    float Wr0[NF], Wr1[NF];
    float2 br;
    if (HOP1) {
#pragma unroll
        for (int ff = 0; ff < NF; ++ff) {
            Wr0[ff] = Wg[(2 * fp) * NF + ff];
            Wr1[ff] = Wg[(2 * fp + 1) * NF + ff];
        }
    } else {
        br.x = bias[2 * fp];
        br.y = bias[2 * fp + 1];
    }

    float ax = 0.f, ay = 0.f;
    int beg = 0, end = 0;
    if (n < N) {
        beg = offsets[n];
        end = offsets[n + 1];
    }
    int e = beg + ep;
    for (; e + 8 < end; e += 16) {
        int s0 = srcs[e];
        int s1 = srcs[e + 8];
        float2 f0 = __half22float2(*(const __half2*)(u + (size_t)s0 * 16 + 2 * fp));
        float2 f1 = __half22float2(*(const __half2*)(u + (size_t)s1 * 16 + 2 * fp));
        ax += f0.x + f1.x;
        ay += f0.y + f1.y;
    }
    for (; e < end; e += 8) {
        float2 f0 = __half22float2(*(const __half2*)(u + (size_t)srcs[e] * 16 + 2 * fp));
        ax += f0.x;
        ay += f0.y;
    }
    ax += __shfl_xor(ax, 8);
    ay += __shfl_xor(ay, 8);
    ax += __shfl_xor(ax, 16);
    ay += __shfl_xor(ay, 16);
    ax += __shfl_xor(ax, 32);
    ay += __shfl_xor(ay, 32);
    if (n >= N) return;
    float2 fs = __half22float2(*(const __half2*)(u + (size_t)n * 16 + 2 * fp));
    ax += fs.x;
    ay += fs.y;
    float dn = dinv[n];
    if (HOP1) {
        float r0 = 0.f, r1 = 0.f;
#pragma unroll
        for (int q = 0; q < 7; ++q) {  // feature pairs 0..6 cover NF=14
            float vx = __shfl(ax, q);
            float vy = __shfl(ay, q);
            r0 += Wr0[2 * q] * vx + Wr0[2 * q + 1] * vy;
            r1 += Wr1[2 * q] * vx + Wr1[2 * q + 1] * vy;
        }
        if (ep == 0) {
            float s = dn * dn;
            *(__half2*)(outh + (size_t)n * 16 + 2 * fp) =
                __halves2half2(__float2half(r0 * s), __float2half(r1 * s));
        }
    } else {
        if (ep == 0) {
            float2 o;
            o.x = dn * ax + br.x;
            o.y = dn * ay + br.y;
            *(float2*)(outf + (size_t)n * DIMOUT + 2 * fp) = o;
        }
    }
}

extern "C" void kernel_launch(void* const* d_in, const int* in_sizes, int n_in,
                              void* d_out, int out_size, void* d_ws, size_t ws_size,
                              hipStream_t stream) {
    const float* x = (const float*)d_in[0];
    const void* edges = d_in[1];
    const float* W = (const float*)d_in[2];
    const float* b = (const float*)d_in[3];
    float* out = (float*)d_out;

    const int N = in_sizes[0] / NF;  // 100000
    const int E = in_sizes[1] / 2;   // 3200000

    char* ws = (char*)d_ws;
    size_t o = 0;
    auto alloc = [&](size_t bytes) -> void* {
        o = (o + 255) & ~(size_t)255;
        void* p = ws + o;
        o += bytes;
        return p;
    };
    int* flag = (int*)alloc(16);
    int* bhist = (int*)alloc((size_t)NBKT * sizeof(int));
    int* gregion = (int*)alloc(((size_t)NBKT + 1) * sizeof(int));
    int* gcur = (int*)alloc((size_t)NBKT * sizeof(int));
    unsigned int* pairs = (unsigned int*)alloc((size_t)E * sizeof(unsigned int));
    int* srcs = (int*)alloc((size_t)E * sizeof(int));
    int* offsets = (int*)alloc(((size_t)N + 1) * sizeof(int));
    float* dinv = (float*)alloc((size_t)N * sizeof(float));
    __half* u0 = (__half*)alloc((size_t)N * 16 * sizeof(__half));
    __half* u1 = (__half*)alloc((size_t)N * 16 * sizeof(__half));
    (void)ws_size;
    (void)n_in;
    (void)out_size;

    hipMemsetAsync(bhist, 0, (size_t)NBKT * sizeof(int), stream);
    k_detect<<<1, 1, 0, stream>>>((const int*)edges, flag);
    k_bhist<<<512, 256, 0, stream>>>(edges, flag, bhist, E);
    k_bscan<<<1, NBKT, 0, stream>>>(bhist, gregion, gcur, E);
    k_scatter1<<<(E + C1 - 1) / C1, 256, 0, stream>>>(edges, flag, gcur, pairs, E);
    k_sort2<<<(N + NPBKT - 1) >> BSH, 256, 0, stream>>>(pairs, gregion, srcs, offsets, dinv, N, E);
    k_prep<<<(N * 8 + 255) / 256, 256, 0, stream>>>(x, dinv, u0, N);

    int hopgrid = (N + 3) / 4;
    k_hop<1><<<hopgrid, 256, 0, stream>>>(u0, srcs, offsets, dinv, W, nullptr, u1, nullptr, N);
    k_hop<0><<<hopgrid, 256, 0, stream>>>(u1, srcs, offsets, dinv, nullptr, b, nullptr, out, N);
}